// Round 5
// baseline (100.291 us; speedup 1.0000x reference)
//
#include <hip/hip_runtime.h>

// r[i,j] = sum_{ii,ij} img[ii,ij] * K[i-ii, j-ij],  K[u,v] = 1/((u+pos0)^2+(v+pos1)^2)
// img: 256x512 f32, pos: 2 f32, out: 32x256 f32.
//
// Round-5: fp16 MFMA formulation. For fixed u = i-ii:
//   r[i,j] += sum_ij img[i-u, ij] * Kr_u[j-ij]   (32x256x512 GEMM, B Toeplitz)
// B-fragments come straight from a reversed K-row held in 8 phase-shifted LDS
// copies (solves 2B-granular b128 alignment). A = img slab (fp16, XOR-swizzled).
// Grid: 36 u-groups(8 u, shared 39-row slab) x 4 j-chunks(64) x 4 k-chunks(128)
// = 576 blocks, all co-resident. Non-atomic partials to d_ws; stage-2 sums.
// K scaled by 256 so all fp16 K values are normal (subnormal flush would lose
// the ~4.6-magnitude far-field tail).

typedef _Float16 half8 __attribute__((ext_vector_type(8)));
typedef float f32x4 __attribute__((ext_vector_type(4)));

constexpr int W = 512;
constexpr int NG = 36, JCN = 4, KCN = 4;
constexpr int GRID1 = NG * JCN * KCN;      // 576
constexpr int SB = 216;                    // phase-copy elements (432B stride)
constexpr float KSCALE = 256.0f;

__global__ __launch_bounds__(256, 4) void corr_mfma(
    const float* __restrict__ img, const float* __restrict__ pos,
    float* __restrict__ ws)
{
    __shared__ __align__(16) _Float16 S[39 * 128];   // img slab, 256B/row, XOR-swz
    __shared__ __align__(16) _Float16 Kc[8 * SB];    // 8 phase copies of rev K row
    __shared__ __align__(16) float red[2048];        // 32 x 64 block partial

    const int tid = threadIdx.x;
    const int bid = blockIdx.x;
    const int kc = bid & 3, jc = (bid >> 2) & 3, g = bid >> 4;
    const int k0 = kc * 128, j0 = jc * 64;
    const int u0 = -255 + 8 * g;

    const float p0 = pos[0], p1 = pos[1];

    for (int z = tid; z < 2048; z += 256) red[z] = 0.0f;

    // ---- stage A slab: S[rr][.] = img[R0+rr][k0..k0+127] fp16 (zero outside)
    const int R0 = -u0 - 7;
    for (int un = tid; un < 39 * 16; un += 256) {
        const int rr = un >> 4, sg = un & 15;
        const int irow = R0 + rr;
        float4 f0 = make_float4(0.f, 0.f, 0.f, 0.f), f1 = f0;
        if (0 <= irow && irow < 256) {
            const float4* gp = (const float4*)(img + irow * W + k0 + sg * 8);
            f0 = gp[0]; f1 = gp[1];
        }
        half8 hv;
        hv[0] = (_Float16)f0.x; hv[1] = (_Float16)f0.y;
        hv[2] = (_Float16)f0.z; hv[3] = (_Float16)f0.w;
        hv[4] = (_Float16)f1.x; hv[5] = (_Float16)f1.y;
        hv[6] = (_Float16)f1.z; hv[7] = (_Float16)f1.w;
        const int c = (sg * 16) ^ ((rr & 7) << 4);
        *(half8*)((char*)S + rr * 256 + c) = hv;
    }

    const int lane = tid & 63;
    const int wv = tid >> 6;          // wave owns k-step ks = wv (32 k each)
    const int m = lane & 15, hq = lane >> 4;

    // B-fragment byte offsets in Kc (d-independent): element t0..t0+7 of
    // reversed row R[t] = Kr[amax - t]; copy p holds R shifted by p.
    const int amax = j0 - k0 + 63;
    int boff[4];
#pragma unroll
    for (int nt = 0; nt < 4; ++nt) {
        const int t0 = 63 - 16 * nt - m + 32 * wv + 8 * hq;
        const int p = t0 & 7;
        boff[nt] = p * 432 + 2 * (t0 - p);
    }
    const int cA = 64 * wv + 16 * hq;  // A col byte base (16B-unit aligned)

    f32x4 acc[2][4];
#pragma unroll
    for (int mt = 0; mt < 2; ++mt)
#pragma unroll
        for (int nt = 0; nt < 4; ++nt)
            acc[mt][nt] = (f32x4){0.f, 0.f, 0.f, 0.f};

#pragma unroll 1
    for (int d = 0; d < 8; ++d) {
        __syncthreads();               // prev compute done before Kc overwrite
        {   // build 8 phase copies for u = u0 + d: Kc[p][s] = R[s+p]
            const float dxu = (float)(u0 + d) + p0;
            const float dx2 = dxu * dxu;
            if (tid < SB) {
#pragma unroll
                for (int p = 0; p < 8; ++p) {
                    const float dy = (float)(amax - tid - p) + p1;
                    Kc[p * SB + tid] =
                        (_Float16)(KSCALE * __builtin_amdgcn_rcpf(dx2 + dy * dy));
                }
            }
        }
        __syncthreads();

        // A-frags: row rr = 16*mt + m + 7 - d  (slab window slides with d)
        const int rr0 = m + 7 - d;
        const int rr1 = rr0 + 16;
        const half8 af0 = *(const half8*)((const char*)S + rr0 * 256 + (cA ^ ((rr0 & 7) << 4)));
        const half8 af1 = *(const half8*)((const char*)S + rr1 * 256 + (cA ^ ((rr1 & 7) << 4)));

#pragma unroll
        for (int nt = 0; nt < 4; ++nt) {
            const half8 b = *(const half8*)((const char*)Kc + boff[nt]);
            acc[0][nt] = __builtin_amdgcn_mfma_f32_16x16x32_f16(af0, b, acc[0][nt], 0, 0, 0);
            acc[1][nt] = __builtin_amdgcn_mfma_f32_16x16x32_f16(af1, b, acc[1][nt], 0, 0, 0);
        }
    }

    // ---- reduce the 4 waves' k-partials in LDS, write block partial to ws
    __syncthreads();
#pragma unroll
    for (int mt = 0; mt < 2; ++mt)
#pragma unroll
        for (int nt = 0; nt < 4; ++nt)
#pragma unroll
            for (int q = 0; q < 4; ++q)
                atomicAdd(&red[(16 * mt + hq * 4 + q) * 64 + 16 * nt + m],
                          acc[mt][nt][q]);
    __syncthreads();

    {
        f32x4* wp = (f32x4*)(ws + bid * 2048);
        const f32x4* rv = (const f32x4*)red;
        wp[tid * 2]     = rv[tid * 2];
        wp[tid * 2 + 1] = rv[tid * 2 + 1];
    }
}

__global__ __launch_bounds__(256) void corr_sum(const float* __restrict__ ws,
                                               float* __restrict__ out)
{
    const int o = blockIdx.x * 256 + threadIdx.x;
    const int i = o >> 8, j = o & 255;
    const int jc = j >> 6, jl = j & 63;
    const int cell = i * 64 + jl;
    float s0 = 0.f, s1 = 0.f, s2 = 0.f, s3 = 0.f;
#pragma unroll 4
    for (int g = 0; g < NG; ++g) {
        const float* b = ws + (size_t)((g * JCN + jc) * KCN) * 2048 + cell;
        s0 += b[0];
        s1 += b[2048];
        s2 += b[2 * 2048];
        s3 += b[3 * 2048];
    }
    out[o] = (s0 + s1 + s2 + s3) * (1.0f / KSCALE);
}

extern "C" void kernel_launch(void* const* d_in, const int* in_sizes, int n_in,
                              void* d_out, int out_size, void* d_ws, size_t ws_size,
                              hipStream_t stream) {
    const float* img = (const float*)d_in[0];
    const float* pos = (const float*)d_in[1];
    float* out = (float*)d_out;
    float* wsf = (float*)d_ws;   // 576 * 2048 * 4B = 4.7 MB partials

    corr_mfma<<<GRID1, 256, 0, stream>>>(img, pos, wsf);
    corr_sum<<<32, 256, 0, stream>>>(wsf, out);
}